// Round 5
// baseline (358.968 us; speedup 1.0000x reference)
//
#include <hip/hip_runtime.h>

// ECA / frequency-channel-attention for MI355X (gfx950).
// Pipeline: prep D(f16) -> per-(b,c-chunk) DCT energy via f16 MFMA ->
// reduce partials -> top16+MLP+sigmoid -> scale x by att[b].

typedef __attribute__((ext_vector_type(8))) _Float16 half8;
typedef __attribute__((ext_vector_type(16))) float f32x16;

#define NCH 32   // channel chunks per batch
#define CPB 4    // channel slices per block (NCH*CPB == 128)

#define Z16 {0.f,0.f,0.f,0.f,0.f,0.f,0.f,0.f,0.f,0.f,0.f,0.f,0.f,0.f,0.f,0.f}

// XOR-swizzled byte offset for a [128][128] 2-byte LDS tile (guide G4/T2):
// row-major stride-256B rows are a heavy bank conflict for b128 reads.
#define SWZ(row, c) (((((row) * 128 + (c)) * 2)) ^ (((row) & 7) << 4))

__device__ __forceinline__ unsigned short f2h(float f) {
    union { _Float16 h; unsigned short u; } cv;
    cv.h = (_Float16)f;
    return cv.u;
}
__device__ __forceinline__ unsigned int pack2(float a, float b) {
    return (unsigned int)f2h(a) | ((unsigned int)f2h(b) << 16);
}

// D[k][n] = s_k * cos(pi*(2n+1)k / 256), s_0 = sqrt(1/128), else sqrt(2/128)=1/8
__global__ __launch_bounds__(256) void dct_prep(unsigned short* __restrict__ Dm) {
    int i = blockIdx.x * 256 + threadIdx.x;   // 0..16383
    int k = i >> 7, n = i & 127;
    float s = (k == 0) ? 0.08838834764831845f : 0.125f;
    float ang = (float)((2 * n + 1) * k) * 0.012271846303085130f; // * pi/256
    Dm[i] = f2h(s * cosf(ang));
}

// One block = (b, chunk of CPB channel slices). 512 threads = 8 waves (4x2 tile grid).
// Per slice: stage A: P = X @ D^T ; stage B: dct2 = D @ P ; en += |dct2|.
__global__ __launch_bounds__(512) void dct_energy_kernel(
    const float* __restrict__ x, const unsigned short* __restrict__ Dm,
    float* __restrict__ energy, float* __restrict__ partial)
{
    __shared__ __attribute__((aligned(16))) unsigned short Xs[128 * 128]; // f16 bits
    __shared__ __attribute__((aligned(16))) unsigned short Ps[128 * 128]; // P^T f16 bits

    const int b = blockIdx.x;
    const int chunk = blockIdx.y;
    const int tid = threadIdx.x;
    const int lane = tid & 63;
    const int wid = tid >> 6;      // 0..7
    const int wm = wid >> 1;       // 0..3: 32-row band
    const int wn = wid & 1;        // 0..1: 64-col band
    const int l31 = lane & 31;
    const int hi = lane >> 5;      // 0/1

    const float4* xb4 = (const float4*)(x + (((size_t)(b * 128 + chunk * CPB)) << 14));

    float en0[16], en1[16];
#pragma unroll
    for (int r = 0; r < 16; ++r) { en0[r] = 0.f; en1[r] = 0.f; }

    const int rowX = 32 * wm + l31;          // A rows (stage A) in X
    const int k2a = 64 * wn + l31;           // output col / P^T row
    const int dOffA0 = k2a * 128;            // D rows used as B-operand (stage A)
    const int dOffA1 = (k2a + 32) * 128;
    const int dOffB = (32 * wm + l31) * 128; // D rows used as A-operand (stage B)

    // prologue: stage slice 0 into Xs
    float4 ld[8];
#pragma unroll
    for (int i = 0; i < 8; ++i) ld[i] = xb4[i * 512 + tid];
#pragma unroll
    for (int i = 0; i < 8; ++i) {
        int fidx = i * 512 + tid;
        int row = fidx >> 5, c = (fidx & 31) << 2;
        uint2 v; v.x = pack2(ld[i].x, ld[i].y); v.y = pack2(ld[i].z, ld[i].w);
        *(uint2*)((char*)Xs + SWZ(row, c)) = v;
    }
    __syncthreads();

    for (int s = 0; s < CPB; ++s) {
        // issue next slice's global loads early (hide HBM under MFMA)
        if (s + 1 < CPB) {
            const float4* nx = xb4 + ((size_t)(s + 1) << 12);
#pragma unroll
            for (int i = 0; i < 8; ++i) ld[i] = nx[i * 512 + tid];
        }

        // ---- stage A: P = X @ D^T  (A=X rows from LDS, B=D^T cols == D rows from global/L1)
        f32x16 acc0 = Z16, acc1 = Z16;
#pragma unroll
        for (int kk = 0; kk < 8; ++kk) {
            int c0 = kk * 16 + hi * 8;
            half8 aX = *(const half8*)((const char*)Xs + SWZ(rowX, c0));
            half8 bD0 = *(const half8*)(const void*)(Dm + dOffA0 + c0);
            half8 bD1 = *(const half8*)(const void*)(Dm + dOffA1 + c0);
            acc0 = __builtin_amdgcn_mfma_f32_32x32x16_f16(aX, bD0, acc0, 0, 0, 0);
            acc1 = __builtin_amdgcn_mfma_f32_32x32x16_f16(aX, bD1, acc1, 0, 0, 0);
        }
        // write P^T (f16) to LDS. C/D layout: col=lane&31, row=(reg&3)+8*(reg>>2)+4*hi
#pragma unroll
        for (int g = 0; g < 4; ++g) {
            int h0 = 32 * wm + 8 * g + 4 * hi;
            uint2 v0; v0.x = pack2(acc0[4 * g + 0], acc0[4 * g + 1]);
            v0.y = pack2(acc0[4 * g + 2], acc0[4 * g + 3]);
            *(uint2*)((char*)Ps + SWZ(k2a, h0)) = v0;
            uint2 v1; v1.x = pack2(acc1[4 * g + 0], acc1[4 * g + 1]);
            v1.y = pack2(acc1[4 * g + 2], acc1[4 * g + 3]);
            *(uint2*)((char*)Ps + SWZ(k2a + 32, h0)) = v1;
        }
        __syncthreads();   // P^T visible; Xs reads done -> Xs free to overwrite

        // ---- stage B: dct2 = D @ P  (A=D rows from global/L1, B=P cols == P^T rows from LDS)
        f32x16 d0 = Z16, d1 = Z16;
#pragma unroll
        for (int kk = 0; kk < 8; ++kk) {
            int c0 = kk * 16 + hi * 8;
            half8 aD = *(const half8*)(const void*)(Dm + dOffB + c0);
            half8 bP0 = *(const half8*)((const char*)Ps + SWZ(k2a, c0));
            half8 bP1 = *(const half8*)((const char*)Ps + SWZ(k2a + 32, c0));
            d0 = __builtin_amdgcn_mfma_f32_32x32x16_f16(aD, bP0, d0, 0, 0, 0);
            d1 = __builtin_amdgcn_mfma_f32_32x32x16_f16(aD, bP1, d1, 0, 0, 0);
        }
#pragma unroll
        for (int r = 0; r < 16; ++r) { en0[r] += fabsf(d0[r]); en1[r] += fabsf(d1[r]); }

        // stage next X slice into LDS (after barrier: all stage-A reads of Xs done)
        if (s + 1 < CPB) {
#pragma unroll
            for (int i = 0; i < 8; ++i) {
                int fidx = i * 512 + tid;
                int row = fidx >> 5, c = (fidx & 31) << 2;
                uint2 v; v.x = pack2(ld[i].x, ld[i].y); v.y = pack2(ld[i].z, ld[i].w);
                *(uint2*)((char*)Xs + SWZ(row, c)) = v;
            }
        }
        __syncthreads();   // Xs ready; Ps free for next stage A
    }

    // emit per-(b,chunk) energy partial (or atomic fallback if ws too small)
    if (partial) {
        float* pb = partial + (((size_t)(b * NCH + chunk)) << 14);
#pragma unroll
        for (int r = 0; r < 16; ++r) {
            int row = 32 * wm + (r & 3) + 8 * (r >> 2) + 4 * hi;
            int idx = row * 128 + k2a;
            pb[idx] = en0[r];
            pb[idx + 32] = en1[r];
        }
    } else {
        float* eb = energy + ((size_t)b << 14);
#pragma unroll
        for (int r = 0; r < 16; ++r) {
            int row = 32 * wm + (r & 3) + 8 * (r >> 2) + 4 * hi;
            int idx = row * 128 + k2a;
            atomicAdd(&eb[idx], en0[r]);
            atomicAdd(&eb[idx + 32], en1[r]);
        }
    }
}

__global__ __launch_bounds__(256) void reduce_energy(
    const float* __restrict__ partial, float* __restrict__ energy)
{
    int g = blockIdx.x * 256 + threadIdx.x;   // 0..262143
    int b = g >> 14, i = g & 16383;
    const float* p = partial + (((size_t)b * NCH) << 14) + i;
    float s = 0.f;
#pragma unroll
    for (int ch = 0; ch < NCH; ++ch) s += p[(size_t)ch << 14];
    energy[g] = s;   // sum over C (divide by 128 later)
}

// one block per batch: iterative top-16 (values cached in regs, 64/thread),
// then thread 0 runs the 16->4->1 MLP + sigmoid.
__global__ __launch_bounds__(256) void topk_mlp(
    const float* __restrict__ energy,
    const float* __restrict__ w1, const float* __restrict__ b1,
    const float* __restrict__ w2, const float* __restrict__ b2,
    float* __restrict__ att)
{
    __shared__ float red[256];
    __shared__ int redi[256];
    __shared__ float topv[16];
    int b = blockIdx.x, t = threadIdx.x;
    const float* eb = energy + ((size_t)b << 14);

    float v[64];
#pragma unroll
    for (int k = 0; k < 64; ++k) v[k] = eb[k * 256 + t];
    unsigned long long mask = ~0ull;

    for (int j = 0; j < 16; ++j) {
        float mv = -1e30f; int mk = 0;
#pragma unroll
        for (int k = 0; k < 64; ++k) {
            float c = ((mask >> k) & 1ull) ? v[k] : -1e30f;
            if (c > mv) { mv = c; mk = k; }
        }
        red[t] = mv; redi[t] = mk * 256 + t;
        __syncthreads();
        for (int s = 128; s > 0; s >>= 1) {
            if (t < s && red[t + s] > red[t]) { red[t] = red[t + s]; redi[t] = redi[t + s]; }
            __syncthreads();
        }
        int widx = redi[0];
        float wval = red[0];
        if (t == (widx & 255)) mask &= ~(1ull << (widx >> 8));
        if (t == 0) topv[j] = wval * (1.0f / 128.0f);   // mean over C
        __syncthreads();
    }

    if (t == 0) {
        float z = b2[0];
#pragma unroll
        for (int jj = 0; jj < 4; ++jj) {
            float a = b1[jj];
#pragma unroll
            for (int i = 0; i < 16; ++i) a += topv[i] * w1[i * 4 + jj];
            a = fmaxf(a, 0.0f);
            z += a * w2[jj];
        }
        att[b] = 1.0f / (1.0f + expf(-z));
    }
}

__global__ __launch_bounds__(256) void scale_kernel(
    const float4* __restrict__ x4, const float* __restrict__ att,
    float4* __restrict__ out4, int n4)
{
    int i = blockIdx.x * 256 + threadIdx.x;
    int stride = gridDim.x * 256;
    for (; i < n4; i += stride) {
        float a = att[i >> 19];   // 2^19 float4 per batch
        float4 v = x4[i];
        v.x *= a; v.y *= a; v.z *= a; v.w *= a;
        out4[i] = v;
    }
}

extern "C" void kernel_launch(void* const* d_in, const int* in_sizes, int n_in,
                              void* d_out, int out_size, void* d_ws, size_t ws_size,
                              hipStream_t stream) {
    const float* x  = (const float*)d_in[0];
    const float* w1 = (const float*)d_in[1];
    const float* b1 = (const float*)d_in[2];
    const float* w2 = (const float*)d_in[3];
    const float* b2 = (const float*)d_in[4];

    char* wsb = (char*)d_ws;
    unsigned short* Dm = (unsigned short*)wsb;               // 32 KB  @ 0
    float* energy = (float*)(wsb + (1 << 15));               // 1 MB   @ 32 KB
    float* att    = (float*)(wsb + (1 << 15) + (1 << 20));   // 64 B
    float* partial = (float*)(wsb + (1 << 21));              // 32 MB  @ 2 MB
    size_t need_partial = (size_t)(1 << 21) + (size_t)16 * NCH * 16384 * 4;
    bool use_partial = (ws_size >= need_partial);

    dct_prep<<<64, 256, 0, stream>>>(Dm);
    if (!use_partial) hipMemsetAsync(energy, 0, (size_t)16 * 16384 * 4, stream);

    dim3 g2(16, NCH);
    dct_energy_kernel<<<g2, 512, 0, stream>>>(x, Dm, energy,
                                              use_partial ? partial : (float*)nullptr);
    if (use_partial) reduce_energy<<<1024, 256, 0, stream>>>(partial, energy);

    topk_mlp<<<16, 256, 0, stream>>>(energy, w1, b1, w2, b2, att);
    scale_kernel<<<2048, 256, 0, stream>>>((const float4*)x, att,
                                           (float4*)d_out, out_size / 4);
}

// Round 8
// 318.320 us; speedup vs baseline: 1.1277x; 1.1277x over previous
//
#include <hip/hip_runtime.h>

// ECA / frequency-channel-attention for MI355X (gfx950).
// Pipeline: prep packed-D(f16) -> per-(b,c-chunk) DCT energy via f16 MFMA ->
// reduce partials -> top16+MLP+sigmoid -> scale x by att[b].

typedef __attribute__((ext_vector_type(8))) _Float16 half8;
typedef __attribute__((ext_vector_type(16))) float f32x16;

#define NCH 32   // channel chunks per batch
#define CPB 4    // channel slices per block (NCH*CPB == 128)

#define Z16 {0.f,0.f,0.f,0.f,0.f,0.f,0.f,0.f,0.f,0.f,0.f,0.f,0.f,0.f,0.f,0.f}

// XOR-swizzled byte offset for a [128][128] 2-byte LDS tile (guide G4/T2).
#define SWZ(row, c) (((((row) * 128 + (c)) * 2)) ^ (((row) & 7) << 4))

__device__ __forceinline__ unsigned short f2h(float f) {
    union { _Float16 h; unsigned short u; } cv;
    cv.h = (_Float16)f;
    return cv.u;
}
__device__ __forceinline__ unsigned int pack2(float a, float b) {
    return (unsigned int)f2h(a) | ((unsigned int)f2h(b) << 16);
}

// Packed MFMA-fragment layout: Dp[kk][hi][r][j] = D[r][16*kk+8*hi+j]
// D[r][c] = s_r * cos(pi*(2c+1)r / 256), s_0 = sqrt(1/128), else 1/8.
// A wave reading its fragment (32 lanes x 16B, same kk/hi) is 512B contiguous.
__global__ __launch_bounds__(256) void dct_prep(unsigned short* __restrict__ Dp) {
    int i = blockIdx.x * 256 + threadIdx.x;   // 0..16383
    int j = i & 7, r = (i >> 3) & 127, hi = (i >> 10) & 1, kk = i >> 11;
    int c = kk * 16 + hi * 8 + j;
    float s = (r == 0) ? 0.08838834764831845f : 0.125f;
    float ang = (float)((2 * c + 1) * r) * 0.012271846303085130f; // * pi/256
    Dp[i] = f2h(s * cosf(ang));
}

// One block = (b, chunk of CPB channel slices). 512 threads = 8 waves (4x2 tile grid).
// Per slice: stage A: P = X @ D^T ; stage B: dct2 = D @ P ; en += |dct2|.
__global__ __launch_bounds__(512) void dct_energy_kernel(
    const float* __restrict__ x, const unsigned short* __restrict__ Dp,
    float* __restrict__ energy, float* __restrict__ partial)
{
    __shared__ __attribute__((aligned(16))) unsigned short Xs[128 * 128]; // f16 bits
    __shared__ __attribute__((aligned(16))) unsigned short Ps[128 * 128]; // P^T f16 bits

    const int b = blockIdx.x;
    const int chunk = blockIdx.y;
    const int tid = threadIdx.x;
    const int lane = tid & 63;
    const int wid = tid >> 6;      // 0..7
    const int wm = wid >> 1;       // 0..3: 32-row band
    const int wn = wid & 1;        // 0..1: 64-col band
    const int l31 = lane & 31;
    const int hi = lane >> 5;      // 0/1

    const float4* xb4 = (const float4*)(x + (((size_t)(b * 128 + chunk * CPB)) << 14));

    float en0[16], en1[16];
#pragma unroll
    for (int r = 0; r < 16; ++r) { en0[r] = 0.f; en1[r] = 0.f; }

    const int rowX = 32 * wm + l31;          // A rows (stage A) in X; also D rows (stage B)
    const int k2a = 64 * wn + l31;           // output col / P^T row; D rows (stage A B-op)
    // Packed-D per-lane bases (in halves); per-kk add (kk*2+hi)<<10.
    const unsigned short* dB0 = Dp + k2a * 8;
    const unsigned short* dB1 = Dp + (k2a + 32) * 8;
    const unsigned short* dA  = Dp + rowX * 8;

    // prologue: stage slice 0 into Xs
    float4 ld[8];
#pragma unroll
    for (int i = 0; i < 8; ++i) ld[i] = xb4[i * 512 + tid];
#pragma unroll
    for (int i = 0; i < 8; ++i) {
        int fidx = i * 512 + tid;
        int row = fidx >> 5, c = (fidx & 31) << 2;
        uint2 v; v.x = pack2(ld[i].x, ld[i].y); v.y = pack2(ld[i].z, ld[i].w);
        *(uint2*)((char*)Xs + SWZ(row, c)) = v;
    }
    __syncthreads();

    for (int s = 0; s < CPB; ++s) {
        // issue next slice's global loads early (hide HBM under MFMA)
        if (s + 1 < CPB) {
            const float4* nx = xb4 + ((size_t)(s + 1) << 12);
#pragma unroll
            for (int i = 0; i < 8; ++i) ld[i] = nx[i * 512 + tid];
        }

        // ---- stage A: P = X @ D^T  (A=X rows from LDS, B=packed D fragments, coalesced)
        f32x16 acc0 = Z16, acc1 = Z16;
#pragma unroll
        for (int kk = 0; kk < 8; ++kk) {
            int c0 = kk * 16 + hi * 8;
            int kb = (kk * 2 + hi) << 10;    // fragment-table offset (halves)
            half8 aX = *(const half8*)((const char*)Xs + SWZ(rowX, c0));
            half8 bD0 = *(const half8*)(const void*)(dB0 + kb);
            half8 bD1 = *(const half8*)(const void*)(dB1 + kb);
            acc0 = __builtin_amdgcn_mfma_f32_32x32x16_f16(aX, bD0, acc0, 0, 0, 0);
            acc1 = __builtin_amdgcn_mfma_f32_32x32x16_f16(aX, bD1, acc1, 0, 0, 0);
        }
        // write P^T (f16) to LDS. C/D layout: col=lane&31, row=(reg&3)+8*(reg>>2)+4*hi
#pragma unroll
        for (int g = 0; g < 4; ++g) {
            int h0 = 32 * wm + 8 * g + 4 * hi;
            uint2 v0; v0.x = pack2(acc0[4 * g + 0], acc0[4 * g + 1]);
            v0.y = pack2(acc0[4 * g + 2], acc0[4 * g + 3]);
            *(uint2*)((char*)Ps + SWZ(k2a, h0)) = v0;
            uint2 v1; v1.x = pack2(acc1[4 * g + 0], acc1[4 * g + 1]);
            v1.y = pack2(acc1[4 * g + 2], acc1[4 * g + 3]);
            *(uint2*)((char*)Ps + SWZ(k2a + 32, h0)) = v1;
        }
        __syncthreads();   // P^T visible; Xs reads done -> Xs free to overwrite

        // ---- stage B: dct2 = D @ P  (A=packed D fragments, B=P^T rows from LDS)
        f32x16 d0 = Z16, d1 = Z16;
#pragma unroll
        for (int kk = 0; kk < 8; ++kk) {
            int c0 = kk * 16 + hi * 8;
            int kb = (kk * 2 + hi) << 10;
            half8 aD = *(const half8*)(const void*)(dA + kb);
            half8 bP0 = *(const half8*)((const char*)Ps + SWZ(k2a, c0));
            half8 bP1 = *(const half8*)((const char*)Ps + SWZ(k2a + 32, c0));
            d0 = __builtin_amdgcn_mfma_f32_32x32x16_f16(aD, bP0, d0, 0, 0, 0);
            d1 = __builtin_amdgcn_mfma_f32_32x32x16_f16(aD, bP1, d1, 0, 0, 0);
        }
#pragma unroll
        for (int r = 0; r < 16; ++r) { en0[r] += fabsf(d0[r]); en1[r] += fabsf(d1[r]); }

        // stage next X slice into LDS (after barrier: all stage-A reads of Xs done)
        if (s + 1 < CPB) {
#pragma unroll
            for (int i = 0; i < 8; ++i) {
                int fidx = i * 512 + tid;
                int row = fidx >> 5, c = (fidx & 31) << 2;
                uint2 v; v.x = pack2(ld[i].x, ld[i].y); v.y = pack2(ld[i].z, ld[i].w);
                *(uint2*)((char*)Xs + SWZ(row, c)) = v;
            }
        }
        __syncthreads();   // Xs ready; Ps free for next stage A
    }

    // emit per-(b,chunk) energy partial (or atomic fallback if ws too small)
    if (partial) {
        float* pb = partial + (((size_t)(b * NCH + chunk)) << 14);
#pragma unroll
        for (int r = 0; r < 16; ++r) {
            int row = 32 * wm + (r & 3) + 8 * (r >> 2) + 4 * hi;
            int idx = row * 128 + k2a;
            pb[idx] = en0[r];
            pb[idx + 32] = en1[r];
        }
    } else {
        float* eb = energy + ((size_t)b << 14);
#pragma unroll
        for (int r = 0; r < 16; ++r) {
            int row = 32 * wm + (r & 3) + 8 * (r >> 2) + 4 * hi;
            int idx = row * 128 + k2a;
            atomicAdd(&eb[idx], en0[r]);
            atomicAdd(&eb[idx + 32], en1[r]);
        }
    }
}

__global__ __launch_bounds__(256) void reduce_energy(
    const float* __restrict__ partial, float* __restrict__ energy)
{
    int g = blockIdx.x * 256 + threadIdx.x;   // 0..262143
    int b = g >> 14, i = g & 16383;
    const float* p = partial + (((size_t)b * NCH) << 14) + i;
    float s = 0.f;
#pragma unroll
    for (int ch = 0; ch < NCH; ++ch) s += p[(size_t)ch << 14];
    energy[g] = s;   // sum over C (divide by 128 later)
}

// one block per batch, 1024 threads: iterative top-16 via register scan +
// wave shuffle reduce + 16-entry LDS final (2 barriers/round).
__global__ __launch_bounds__(1024) void topk_mlp(
    const float* __restrict__ energy,
    const float* __restrict__ w1, const float* __restrict__ b1,
    const float* __restrict__ w2, const float* __restrict__ b2,
    float* __restrict__ att)
{
    __shared__ float wv[16];
    __shared__ int   wi[16];
    __shared__ float winv_s;
    __shared__ int   wini_s;
    __shared__ float topv[16];
    int b = blockIdx.x, t = threadIdx.x;
    int lane = t & 63, wid = t >> 6;
    const float* eb = energy + ((size_t)b << 14);

    float v[16];
#pragma unroll
    for (int k = 0; k < 16; ++k) v[k] = eb[k * 1024 + t];
    unsigned mask = 0xFFFFu;

    for (int j = 0; j < 16; ++j) {
        float mv = -1e30f; int mi = 0;
#pragma unroll
        for (int k = 0; k < 16; ++k) {
            if ((mask >> k) & 1u) {
                float c = v[k];
                if (c > mv) { mv = c; mi = k * 1024 + t; }
            }
        }
#pragma unroll
        for (int off = 32; off >= 1; off >>= 1) {
            float ov = __shfl_down(mv, off);
            int   oi = __shfl_down(mi, off);
            if (ov > mv) { mv = ov; mi = oi; }
        }
        if (lane == 0) { wv[wid] = mv; wi[wid] = mi; }
        __syncthreads();
        if (t == 0) {
            float bv = wv[0]; int bi = wi[0];
#pragma unroll
            for (int w = 1; w < 16; ++w)
                if (wv[w] > bv) { bv = wv[w]; bi = wi[w]; }
            winv_s = bv; wini_s = bi;
            topv[j] = bv * (1.0f / 128.0f);   // mean over C
        }
        __syncthreads();
        int gw = wini_s;
        if (t == (gw & 1023)) mask &= ~(1u << (gw >> 10));
        // safe: owner reads wini_s before reaching next round's first barrier,
        // and wini_s is only rewritten after that barrier.
    }

    if (t == 0) {
        float z = b2[0];
#pragma unroll
        for (int jj = 0; jj < 4; ++jj) {
            float a = b1[jj];
#pragma unroll
            for (int i = 0; i < 16; ++i) a += topv[i] * w1[i * 4 + jj];
            a = fmaxf(a, 0.0f);
            z += a * w2[jj];
        }
        att[b] = 1.0f / (1.0f + expf(-z));
    }
}

__global__ __launch_bounds__(256) void scale_kernel(
    const float4* __restrict__ x4, const float* __restrict__ att,
    float4* __restrict__ out4, int n4)
{
    int i = blockIdx.x * 256 + threadIdx.x;
    int stride = gridDim.x * 256;
    for (; i < n4; i += stride) {
        float a = att[i >> 19];   // 2^19 float4 per batch
        float4 v = x4[i];
        v.x *= a; v.y *= a; v.z *= a; v.w *= a;
        out4[i] = v;
    }
}

extern "C" void kernel_launch(void* const* d_in, const int* in_sizes, int n_in,
                              void* d_out, int out_size, void* d_ws, size_t ws_size,
                              hipStream_t stream) {
    const float* x  = (const float*)d_in[0];
    const float* w1 = (const float*)d_in[1];
    const float* b1 = (const float*)d_in[2];
    const float* w2 = (const float*)d_in[3];
    const float* b2 = (const float*)d_in[4];

    char* wsb = (char*)d_ws;
    unsigned short* Dp = (unsigned short*)wsb;               // 32 KB  @ 0
    float* energy = (float*)(wsb + (1 << 15));               // 1 MB   @ 32 KB
    float* att    = (float*)(wsb + (1 << 15) + (1 << 20));   // 64 B
    float* partial = (float*)(wsb + (1 << 21));              // 32 MB  @ 2 MB
    size_t need_partial = (size_t)(1 << 21) + (size_t)16 * NCH * 16384 * 4;
    bool use_partial = (ws_size >= need_partial);

    dct_prep<<<64, 256, 0, stream>>>(Dp);
    if (!use_partial) hipMemsetAsync(energy, 0, (size_t)16 * 16384 * 4, stream);

    dim3 g2(16, NCH);
    dct_energy_kernel<<<g2, 512, 0, stream>>>(x, Dp, energy,
                                              use_partial ? partial : (float*)nullptr);
    if (use_partial) reduce_energy<<<1024, 256, 0, stream>>>(partial, energy);

    topk_mlp<<<16, 1024, 0, stream>>>(energy, w1, b1, w2, b2, att);
    scale_kernel<<<2048, 256, 0, stream>>>((const float4*)x, att,
                                           (float4*)d_out, out_size / 4);
}